// Round 9
// baseline (270.007 us; speedup 1.0000x reference)
//
#include <hip/hip_runtime.h>
#include <stdint.h>

// ---------------------------------------------------------------------------
// LatticeCNN on MI355X — round 9.
//
// Math (validated rounds 2-8):
//   out(x,y) = leaky( X[x,y]·W1[clsx][clsy] + S2 + S3 + S4 + bias )
//   S3 = sum_{a<px} V[a][y],  V[a][y] = X[24+a,y]·AS[a][py]
//   S2 = sum_{b<py} U[b][x],  U[b][x] = X[x,24+b]·SB[px][b]
//   S4 = sum_{a<px,b<py} T[a][b],  T[a][b] = X[24+a,24+b]·mw[a][b]
//   Wall[slot][gf] = sum_k L[slot][k]·PBg[gf][k], K=128=[mw;jw], L closed-form.
//
// Round-8 post-mortem: all top-5 = harness d_ws poison fills; our kernel sum
// ~100us vs dur 249 -> ~7us/dispatch chain overhead dominates (11 serial
// dispatches). Round-9: 11 -> 7 dispatches. (1) scans fused into final_gemm
// (raw V/U/T summed there; 9.4MB lives in L2 so re-reads are L2-hits);
// (2) dtype detect inlined per-block (flag dependency gone) so L-build, bias,
// pack, transpose_in fuse into ONE mega dispatch; (3) transpose_out detects
// inline.
//
// Workspace (~88MB of 256MB):
//   Xt0@0 (8.4) | A1@9 (16.8) | Wall0@26 (7.4) | Wall1@34 (14.7)
//   Out2@49 (16.8) | PBg0@66 (2.1) | PBg1@69 (4.2) | L@74 | bias@75
//   V@76 (4.2) | U@81 (4.2) | T@86 (1.05)   (bf16 raw corrections)
// ---------------------------------------------------------------------------

typedef __attribute__((ext_vector_type(8))) short short8;
typedef __attribute__((ext_vector_type(4))) float floatx4;

__device__ __forceinline__ float bf2f(unsigned short u) {
  union { uint32_t u; float f; } c; c.u = ((uint32_t)u) << 16; return c.f;
}
__device__ __forceinline__ unsigned short f2bf(float f) {
  union { float f; uint32_t u; } c; c.f = f;
  uint32_t u = c.u;
  uint32_t r = (u + 0x7FFFu + ((u >> 16) & 1u)) >> 16;
  return (unsigned short)r;
}

// Per-block dtype detect: 1 = fp32, 0 = bf16. Reads x's first 256 u16 words;
// bf16 normal data -> ~all exponents plausible; fp32-viewed-as-u16 -> ~55%.
__device__ __forceinline__ int detect_fp32_block(
    const unsigned short* __restrict__ xa, int* scnt) {
  if (threadIdx.x == 0) *scnt = 0;
  __syncthreads();
  unsigned short v = xa[threadIdx.x & 255];
  int e = (v >> 7) & 0xFF;
  int ok = (v == 0) || (e >= 110 && e <= 140);
  atomicAdd(scnt, ok);
  __syncthreads();
  return (*scnt >= 240) ? 0 : 1;
}

// Weight slot bases inside Wall [slot][G][F]
#define SLOT_W1 0    // 225 combined pointwise slots (clsx*15+clsy)
#define SLOT_SB 225  // 64 slots (px*8+b)
#define SLOT_AS 289  // 64 slots (a*8+py)
#define SLOT_M  353  // 64 slots (a*8+b)
#define N_SLOTS 417
#define N_SLOTS_PAD 448

// Mega setup dispatch (1D, 5345 blocks of 256):
//   [0,224)        : L[448][128] closed-form coefficient matrix
//   224            : bias build (inline detect)
//   [225,1249)     : pack mw||jw -> PBg[g*F+f][128] (inline detect)
//   [1249,5345)    : transpose_in x[4096][1024] -> Xt0[pos][m][f] (inline det)
__global__ __launch_bounds__(256) void mega_setup(
    const unsigned short* __restrict__ xa,
    const void* __restrict__ mw0, const void* __restrict__ jw0,
    const void* __restrict__ mw1, const void* __restrict__ jw1,
    const void* __restrict__ mb0, const void* __restrict__ jb0,
    const void* __restrict__ mb1, const void* __restrict__ jb1,
    unsigned short* __restrict__ L, float* __restrict__ bias0,
    float* __restrict__ bias1, unsigned short* __restrict__ PBg0,
    unsigned short* __restrict__ PBg1, unsigned short* __restrict__ Xt0) {
  __shared__ unsigned short shbuf[128 * 33];
  __shared__ int scnt;
  int blk = blockIdx.x;

  if (blk < 224) {  // ---- L build ----
    int tid = blk * 256 + threadIdx.x;  // 448*128 entries
    int slot = tid >> 7, k = tid & 127;
    int isj = k >= 64, ab = k & 63, a = ab >> 3, b = ab & 7;
    float v = 0.f;
    if (slot < 225) {
      int cx = slot / 15, cy = slot % 15;
      int pmx = cx < 7 ? cx : 7, pxx = cx > 7 ? cx - 7 : 0;
      int pmy = cy < 7 ? cy : 7, pyy = cy > 7 ? cy - 7 : 0;
      if (!isj) v = (a >= pxx && b >= pyy) ? 0.5f : 0.f;
      else      v = (a <= pmx && b <= pmy) ? 0.5f : 0.f;
    } else if (slot < 289) {
      int s = slot - SLOT_SB, px = s >> 3, b0 = s & 7;
      if (!isj) v = (a >= px && b == b0) ? 0.5f : 0.f;
    } else if (slot < 353) {
      int s = slot - SLOT_AS, a0 = s >> 3, py = s & 7;
      if (!isj) v = (a == a0 && b >= py) ? 0.5f : 0.f;
    } else if (slot < 417) {
      int s = slot - SLOT_M, a0 = s >> 3, b0 = s & 7;
      if (!isj) v = (a == a0 && b == b0) ? 0.5f : 0.f;
    }
    L[tid] = f2bf(v);
    return;
  }

  if (blk == 224) {  // ---- bias ----
    int fp32 = detect_fp32_block(xa, &scnt);
    int g = threadIdx.x & 127;
    const void* mb = (threadIdx.x < 128) ? mb0 : mb1;
    const void* jb = (threadIdx.x < 128) ? jb0 : jb1;
    float* bo = (threadIdx.x < 128) ? bias0 : bias1;
    float m = fp32 ? ((const float*)mb)[g] : bf2f(((const unsigned short*)mb)[g]);
    float j = fp32 ? ((const float*)jb)[g] : bf2f(((const unsigned short*)jb)[g]);
    bo[g] = 0.5f * (m + j);
    return;
  }

  int tx = threadIdx.x & 31, ty = threadIdx.x >> 5;  // (32,8) view

  if (blk < 1249) {  // ---- pack weights: gf-order, K=128 ----
    int fp32 = detect_fp32_block(xa, &scnt);
    int pblk = blk - 225;           // [0,1024)
    int layer = pblk >> 9;          // 512 per layer
    int rem = pblk & 511;
    int f = rem >> 2, gt = rem & 3;
    int F = layer ? 128 : 64;
    if (f >= F) return;
    int g0 = gt * 32;
    const int G = 128, FG = F * G;
    const void* mw = layer ? mw1 : mw0;
    const void* jw = layer ? jw1 : jw0;
    unsigned short* PB = layer ? PBg1 : PBg0;
    for (int k = ty; k < 128; k += 8) {
      const void* src = (k < 64) ? mw : jw;
      int ab = k & 63;
      size_t idx = (size_t)ab * FG + (size_t)f * G + g0 + tx;
      shbuf[k * 33 + tx] = fp32 ? f2bf(((const float*)src)[idx])
                                : ((const unsigned short*)src)[idx];
    }
    __syncthreads();
    int kk = threadIdx.x & 127, gs = threadIdx.x >> 7;
    for (int gg = gs; gg < 32; gg += 2)
      PB[((size_t)(g0 + gg) * F + f) * 128 + kk] = shbuf[kk * 33 + gg];
    return;
  }

  // ---- transpose_in: x[4096][1024] -> Xt0[1024][4096] ----
  {
    int fp32 = detect_fp32_block(xa, &scnt);
    int tblk = blk - 1249;          // [0,4096)
    int c0 = (tblk & 31) * 32, r0 = (tblk >> 5) * 32;
    const int R = 4096, C = 1024;
    if (fp32) {
#pragma unroll
      for (int i = 0; i < 32; i += 8)
        shbuf[(ty + i) * 33 + tx] =
            f2bf(((const float*)xa)[(size_t)(r0 + ty + i) * C + (c0 + tx)]);
    } else {
#pragma unroll
      for (int i = 0; i < 32; i += 8)
        shbuf[(ty + i) * 33 + tx] = xa[(size_t)(r0 + ty + i) * C + (c0 + tx)];
    }
    __syncthreads();
#pragma unroll
    for (int i = 0; i < 32; i += 8)
      Xt0[(size_t)(c0 + ty + i) * R + (r0 + tx)] = shbuf[tx * 33 + ty + i];
  }
}

// MFMA core: acc[64m x (16*NT)g] += A[64m x K] * Wt[g x K]^T (W pre-offset).
// A fragment: lane holds A[m=lane&15][k=(lane>>4)*8+j]   (16B load)
// B fragment: lane holds Wt[n=lane&15][k=(lane>>4)*8+j]  (16B load)
template <int F, int NT>
__device__ __forceinline__ void mfma_tile(
    const unsigned short* __restrict__ A, const unsigned short* __restrict__ W,
    floatx4 acc[NT], int wave, int n, int q) {
  const unsigned short* a_ptr = A + ((size_t)(wave * 16 + n)) * F + q * 8;
  const unsigned short* w_ptr = W + (size_t)n * F + q * 8;
#pragma unroll
  for (int kk = 0; kk < F; kk += 32) {
    short8 av = *(const short8*)(a_ptr + kk);
#pragma unroll
    for (int t = 0; t < NT; ++t) {
      short8 bv = *(const short8*)(w_ptr + (size_t)t * 16 * F + kk);
      acc[t] = __builtin_amdgcn_mfma_f32_16x16x32_bf16(av, bv, acc[t], 0, 0, 0);
    }
  }
}

// Prep GEMM: Wall[slot][gf] = sum_k L[slot][k]*PBg[gf][k]. Direct store.
// grid (n-tiles of 128 gf, 7 m-tiles of 64 slots, 2 layers).
__global__ __launch_bounds__(256) void prep_gemm2(
    const unsigned short* __restrict__ L,
    const unsigned short* __restrict__ PBg0,
    const unsigned short* __restrict__ PBg1,
    unsigned short* __restrict__ Wall0, unsigned short* __restrict__ Wall1) {
  int layer = blockIdx.z;
  int GF = layer ? 16384 : 8192;
  int n0 = blockIdx.x * 128;
  if (n0 >= GF) return;
  int m0 = blockIdx.y * 64;
  const unsigned short* PB = layer ? PBg1 : PBg0;
  unsigned short* Wall = layer ? Wall1 : Wall0;
  int wave = threadIdx.x >> 6, lane = threadIdx.x & 63;
  int n = lane & 15, q = lane >> 4;
  floatx4 acc[8];
#pragma unroll
  for (int t = 0; t < 8; ++t) acc[t] = (floatx4){0.f, 0.f, 0.f, 0.f};
  mfma_tile<128, 8>(L + (size_t)m0 * 128, PB + (size_t)n0 * 128, acc, wave, n, q);
#pragma unroll
  for (int t = 0; t < 8; ++t) {
    int gcol = n0 + t * 16 + n;
#pragma unroll
    for (int r = 0; r < 4; ++r) {
      int m = m0 + wave * 16 + q * 4 + r;  // C/D: row=(lane>>4)*4+reg
      Wall[(size_t)m * GF + gcol] = f2bf(acc[t][r]);
    }
  }
}

// Correction matmuls: grid (576, 2); gs = g-half. Raw bf16 stores.
//   bid <256 : V[a][y] = X[24+a, y]      * AS[a][py(y)]
//   bid <512 : U[b][x] = X[x, 24+b]      * SB[px(x)][b]
//   else     : T[a][b] = X[24+a, 24+b]   * mw[a][b]
template <int F>
__global__ __launch_bounds__(256) void corr_gemm(
    const unsigned short* __restrict__ Xt, const unsigned short* __restrict__ Wall,
    unsigned short* __restrict__ V, unsigned short* __restrict__ U,
    unsigned short* __restrict__ T) {
  int bid = blockIdx.x, gs = blockIdx.y;
  int wave = threadIdx.x >> 6, lane = threadIdx.x & 63;
  int n = lane & 15, q = lane >> 4;
  int ipos, slot;
  unsigned short* out;
  if (bid < 256) {
    int a = bid >> 5, y = bid & 31;
    int py = y > 24 ? y - 24 : 0;
    ipos = (24 + a) * 32 + y;
    slot = SLOT_AS + a * 8 + py;
    out = V + (size_t)(a * 32 + y) * 8192;
  } else if (bid < 512) {
    int i = bid - 256;
    int b = i >> 5, x = i & 31;
    int px = x > 24 ? x - 24 : 0;
    ipos = x * 32 + 24 + b;
    slot = SLOT_SB + px * 8 + b;
    out = U + (size_t)(b * 32 + x) * 8192;
  } else {
    int i = bid - 512;
    int a = i >> 3, b = i & 7;
    ipos = (24 + a) * 32 + 24 + b;
    slot = SLOT_M + a * 8 + b;
    out = T + (size_t)(a * 8 + b) * 8192;
  }
  floatx4 acc[4];
#pragma unroll
  for (int t = 0; t < 4; ++t) acc[t] = (floatx4){0.f, 0.f, 0.f, 0.f};
  mfma_tile<F, 4>(Xt + (size_t)ipos * 64 * F,
                  Wall + ((size_t)slot * 128 + gs * 64) * F, acc, wave, n, q);
#pragma unroll
  for (int t = 0; t < 4; ++t) {
    int gcol = gs * 64 + t * 16 + n;
#pragma unroll
    for (int r = 0; r < 4; ++r) {
      int m = wave * 16 + q * 4 + r;
      out[(size_t)m * 128 + gcol] = f2bf(acc[t][r]);
    }
  }
}

// term1 + fused correction sums + bias + leaky-relu -> bf16 [pos][m][128].
// grid (1024, 2); gs = g-half. Sums RAW V/U/T tiles (scan fused here; the
// 9.4MB V/U/T set is L2-resident so repeats are L2-hits).
template <int F>
__global__ __launch_bounds__(256) void final_gemm(
    const unsigned short* __restrict__ Xt, const unsigned short* __restrict__ Wall,
    const unsigned short* __restrict__ V, const unsigned short* __restrict__ U,
    const unsigned short* __restrict__ T, const float* __restrict__ bias,
    unsigned short* __restrict__ Out) {
  int pos = blockIdx.x, gs = blockIdx.y;
  int x = pos >> 5, y = pos & 31;
  int wave = threadIdx.x >> 6, lane = threadIdx.x & 63;
  int n = lane & 15, q = lane >> 4;
  int clsx = x < 7 ? x : (x <= 24 ? 7 : x - 17);
  int clsy = y < 7 ? y : (y <= 24 ? 7 : y - 17);
  int px = x > 24 ? x - 24 : 0;
  int py = y > 24 ? y - 24 : 0;

  int rowoff[4], coloff[4];
#pragma unroll
  for (int r = 0; r < 4; ++r) rowoff[r] = (wave * 16 + q * 4 + r) * 128;
#pragma unroll
  for (int t = 0; t < 4; ++t) coloff[t] = gs * 64 + t * 16 + n;

  // Hoisted bias + raw-tile correction sums (overlap the MFMA-loop loads).
  float csum[4][4];
#pragma unroll
  for (int t = 0; t < 4; ++t) {
    float bv = bias[coloff[t]];
#pragma unroll
    for (int r = 0; r < 4; ++r) csum[t][r] = bv;
  }
  for (int a = 0; a < px; ++a) {
    const unsigned short* p = V + (size_t)(a * 32 + y) * 8192;
#pragma unroll
    for (int t = 0; t < 4; ++t)
#pragma unroll
      for (int r = 0; r < 4; ++r) csum[t][r] += bf2f(p[rowoff[r] + coloff[t]]);
  }
  for (int b = 0; b < py; ++b) {
    const unsigned short* p = U + (size_t)(b * 32 + x) * 8192;
#pragma unroll
    for (int t = 0; t < 4; ++t)
#pragma unroll
      for (int r = 0; r < 4; ++r) csum[t][r] += bf2f(p[rowoff[r] + coloff[t]]);
  }
  for (int a = 0; a < px; ++a)
    for (int b = 0; b < py; ++b) {
      const unsigned short* p = T + (size_t)(a * 8 + b) * 8192;
#pragma unroll
      for (int t = 0; t < 4; ++t)
#pragma unroll
        for (int r = 0; r < 4; ++r) csum[t][r] += bf2f(p[rowoff[r] + coloff[t]]);
    }

  floatx4 acc[4];
#pragma unroll
  for (int t = 0; t < 4; ++t) acc[t] = (floatx4){0.f, 0.f, 0.f, 0.f};
  mfma_tile<F, 4>(Xt + (size_t)pos * 64 * F,
                  Wall + ((size_t)(SLOT_W1 + clsx * 15 + clsy) * 128 + gs * 64) * F,
                  acc, wave, n, q);

  unsigned short* o = Out + (size_t)pos * 64 * 128;
#pragma unroll
  for (int t = 0; t < 4; ++t) {
#pragma unroll
    for (int r = 0; r < 4; ++r) {
      float v = acc[t][r] + csum[t][r];
      v = v > 0.f ? v : 0.01f * v;
      o[rowoff[r] + coloff[t]] = f2bf(v);
    }
  }
}

// Transpose Out2[1024][8192] -> d_out [m][g][pos]; dst fp32|bf16 inline det.
__global__ __launch_bounds__(256) void transpose_out(
    const unsigned short* __restrict__ xa, const unsigned short* __restrict__ src,
    unsigned short* __restrict__ d16, float* __restrict__ d32) {
  __shared__ unsigned short tile[32][33];
  __shared__ int scnt;
  int fp32 = detect_fp32_block(xa, &scnt);
  const int R = 1024, C = 8192;
  int tx = threadIdx.x & 31, ty = threadIdx.x >> 5;
  int c0 = blockIdx.x * 32, r0 = blockIdx.y * 32;
#pragma unroll
  for (int i = 0; i < 32; i += 8)
    tile[ty + i][tx] = src[(size_t)(r0 + ty + i) * C + (c0 + tx)];
  __syncthreads();
  if (fp32) {
#pragma unroll
    for (int i = 0; i < 32; i += 8)
      d32[(size_t)(c0 + ty + i) * R + (r0 + tx)] = bf2f(tile[tx][ty + i]);
  } else {
#pragma unroll
    for (int i = 0; i < 32; i += 8)
      d16[(size_t)(c0 + ty + i) * R + (r0 + tx)] = tile[tx][ty + i];
  }
}

extern "C" void kernel_launch(void* const* d_in, const int* in_sizes, int n_in,
                              void* d_out, int out_size, void* d_ws,
                              size_t ws_size, hipStream_t stream) {
  const void* x   = d_in[0];
  const void* mw0 = d_in[5];
  const void* mb0 = d_in[6];
  const void* jw0 = d_in[7];
  const void* jb0 = d_in[8];
  const void* mw1 = d_in[9];
  const void* mb1 = d_in[10];
  const void* jw1 = d_in[11];
  const void* jb1 = d_in[12];

  char* ws = (char*)d_ws;
  const size_t MB = 1u << 20;
  unsigned short* Xt0   = (unsigned short*)(ws + 0);        // 8.4 MB
  unsigned short* A1    = (unsigned short*)(ws + 9 * MB);   // 16.8 MB
  unsigned short* Wall0 = (unsigned short*)(ws + 26 * MB);  // 7.4 MB (448)
  unsigned short* Wall1 = (unsigned short*)(ws + 34 * MB);  // 14.7 MB (448)
  unsigned short* Out2  = (unsigned short*)(ws + 49 * MB);  // 16.8 MB
  unsigned short* PBg0  = (unsigned short*)(ws + 66 * MB);  // 2.1 MB
  unsigned short* PBg1  = (unsigned short*)(ws + 69 * MB);  // 4.2 MB
  unsigned short* L     = (unsigned short*)(ws + 74 * MB);  // 114 KB
  float* bias0 = (float*)(ws + 75 * MB);
  float* bias1 = bias0 + 128;
  unsigned short* V = (unsigned short*)(ws + 76 * MB);      // 4.2 MB
  unsigned short* U = (unsigned short*)(ws + 81 * MB);      // 4.2 MB
  unsigned short* T = (unsigned short*)(ws + 86 * MB);      // 1.05 MB

  mega_setup<<<5345, 256, 0, stream>>>(
      (const unsigned short*)x, mw0, jw0, mw1, jw1, mb0, jb0, mb1, jb1, L,
      bias0, bias1, PBg0, PBg1, Xt0);
  prep_gemm2<<<dim3(128, 7, 2), 256, 0, stream>>>(L, PBg0, PBg1, Wall0, Wall1);

  // ---- Layer 1 (F=64) ----
  corr_gemm<64><<<dim3(576, 2), 256, 0, stream>>>(Xt0, Wall0, V, U, T);
  final_gemm<64><<<dim3(1024, 2), 256, 0, stream>>>(Xt0, Wall0, V, U, T,
                                                    bias0, A1);
  // ---- Layer 2 (F=128) ----
  corr_gemm<128><<<dim3(576, 2), 256, 0, stream>>>(A1, Wall1, V, U, T);
  final_gemm<128><<<dim3(1024, 2), 256, 0, stream>>>(A1, Wall1, V, U, T,
                                                     bias1, Out2);

  // Out2 [pos=1024][m*128+g=8192] -> d_out [m][g][pos]
  transpose_out<<<dim3(256, 32), 256, 0, stream>>>(
      (const unsigned short*)x, Out2, (unsigned short*)d_out, (float*)d_out);
}

// Round 10
// 257.763 us; speedup vs baseline: 1.0475x; 1.0475x over previous
//
#include <hip/hip_runtime.h>
#include <stdint.h>

// ---------------------------------------------------------------------------
// LatticeCNN on MI355X — round 10.
//
// Math (validated rounds 2-9):
//   out(x,y) = leaky( X[x,y]·W1[clsx][clsy] + P2 + P3 + P4 + bias )
//   P3 = prefix_a of V[a][y] = X[24+a,y]·AS[a][py]
//   P2 = prefix_b of U[b][x] = X[x,24+b]·SB[px][b]
//   P4 = 2D prefix of T[a][b] = X[24+a,24+b]·mw[a][b]
//   Wall[slot][gf] = sum_k L[slot][k]·PBg[gf][k], K=128=[mw;jw], L closed-form.
//
// Round-9 post-mortem: scan-fusion into final_gemm REGRESSED (+60us): the
// raw-tile sum is px+py+px*py in [0,63] tiles -> corner-block tail redux
// (final_gemm 52us, Occ 23%, latency-starved). mega_setup fusion WON (~39us).
// Round-10: keep mega_setup + inline-detect transpose_out; restore the r8
// prefix-scan dispatch so final_gemm reads <=3 prescanned tiles (uniform).
// 9 dispatches.
//
// Workspace (~88MB of 256MB):
//   Xt0@0 (8.4) | A1@9 (16.8) | Wall0@26 (7.4) | Wall1@34 (14.7)
//   Out2@49 (16.8) | PBg0@66 (2.1) | PBg1@69 (4.2) | L@74 | bias@75
//   V@76 (4.2) | U@81 (4.2) | T@86 (1.05)   (bf16 corrections, prescanned)
// ---------------------------------------------------------------------------

typedef __attribute__((ext_vector_type(8))) short short8;
typedef __attribute__((ext_vector_type(4))) float floatx4;

__device__ __forceinline__ float bf2f(unsigned short u) {
  union { uint32_t u; float f; } c; c.u = ((uint32_t)u) << 16; return c.f;
}
__device__ __forceinline__ unsigned short f2bf(float f) {
  union { float f; uint32_t u; } c; c.f = f;
  uint32_t u = c.u;
  uint32_t r = (u + 0x7FFFu + ((u >> 16) & 1u)) >> 16;
  return (unsigned short)r;
}

// Per-block dtype detect: 1 = fp32, 0 = bf16 (x's first 256 u16 exponents).
__device__ __forceinline__ int detect_fp32_block(
    const unsigned short* __restrict__ xa, int* scnt) {
  if (threadIdx.x == 0) *scnt = 0;
  __syncthreads();
  unsigned short v = xa[threadIdx.x & 255];
  int e = (v >> 7) & 0xFF;
  int ok = (v == 0) || (e >= 110 && e <= 140);
  atomicAdd(scnt, ok);
  __syncthreads();
  return (*scnt >= 240) ? 0 : 1;
}

// Weight slot bases inside Wall [slot][G][F]
#define SLOT_W1 0    // 225 combined pointwise slots (clsx*15+clsy)
#define SLOT_SB 225  // 64 slots (px*8+b)
#define SLOT_AS 289  // 64 slots (a*8+py)
#define SLOT_M  353  // 64 slots (a*8+b)
#define N_SLOTS 417
#define N_SLOTS_PAD 448

// Mega setup dispatch (1D, 5345 blocks of 256):
//   [0,224)    : L[448][128] closed-form coefficient matrix
//   224        : bias build (inline detect)
//   [225,1249) : pack mw||jw -> PBg[g*F+f][128] (inline detect)
//   [1249,5345): transpose_in x[4096][1024] -> Xt0[pos][m][f] (inline detect)
__global__ __launch_bounds__(256) void mega_setup(
    const unsigned short* __restrict__ xa,
    const void* __restrict__ mw0, const void* __restrict__ jw0,
    const void* __restrict__ mw1, const void* __restrict__ jw1,
    const void* __restrict__ mb0, const void* __restrict__ jb0,
    const void* __restrict__ mb1, const void* __restrict__ jb1,
    unsigned short* __restrict__ L, float* __restrict__ bias0,
    float* __restrict__ bias1, unsigned short* __restrict__ PBg0,
    unsigned short* __restrict__ PBg1, unsigned short* __restrict__ Xt0) {
  __shared__ unsigned short shbuf[128 * 33];
  __shared__ int scnt;
  int blk = blockIdx.x;

  if (blk < 224) {  // ---- L build ----
    int tid = blk * 256 + threadIdx.x;  // 448*128 entries
    int slot = tid >> 7, k = tid & 127;
    int isj = k >= 64, ab = k & 63, a = ab >> 3, b = ab & 7;
    float v = 0.f;
    if (slot < 225) {
      int cx = slot / 15, cy = slot % 15;
      int pmx = cx < 7 ? cx : 7, pxx = cx > 7 ? cx - 7 : 0;
      int pmy = cy < 7 ? cy : 7, pyy = cy > 7 ? cy - 7 : 0;
      if (!isj) v = (a >= pxx && b >= pyy) ? 0.5f : 0.f;
      else      v = (a <= pmx && b <= pmy) ? 0.5f : 0.f;
    } else if (slot < 289) {
      int s = slot - SLOT_SB, px = s >> 3, b0 = s & 7;
      if (!isj) v = (a >= px && b == b0) ? 0.5f : 0.f;
    } else if (slot < 353) {
      int s = slot - SLOT_AS, a0 = s >> 3, py = s & 7;
      if (!isj) v = (a == a0 && b >= py) ? 0.5f : 0.f;
    } else if (slot < 417) {
      int s = slot - SLOT_M, a0 = s >> 3, b0 = s & 7;
      if (!isj) v = (a == a0 && b == b0) ? 0.5f : 0.f;
    }
    L[tid] = f2bf(v);
    return;
  }

  if (blk == 224) {  // ---- bias ----
    int fp32 = detect_fp32_block(xa, &scnt);
    int g = threadIdx.x & 127;
    const void* mb = (threadIdx.x < 128) ? mb0 : mb1;
    const void* jb = (threadIdx.x < 128) ? jb0 : jb1;
    float* bo = (threadIdx.x < 128) ? bias0 : bias1;
    float m = fp32 ? ((const float*)mb)[g] : bf2f(((const unsigned short*)mb)[g]);
    float j = fp32 ? ((const float*)jb)[g] : bf2f(((const unsigned short*)jb)[g]);
    bo[g] = 0.5f * (m + j);
    return;
  }

  int tx = threadIdx.x & 31, ty = threadIdx.x >> 5;  // (32,8) view

  if (blk < 1249) {  // ---- pack weights: gf-order, K=128 ----
    int fp32 = detect_fp32_block(xa, &scnt);
    int pblk = blk - 225;           // [0,1024)
    int layer = pblk >> 9;          // 512 per layer
    int rem = pblk & 511;
    int f = rem >> 2, gt = rem & 3;
    int F = layer ? 128 : 64;
    if (f >= F) return;
    int g0 = gt * 32;
    const int G = 128, FG = F * G;
    const void* mw = layer ? mw1 : mw0;
    const void* jw = layer ? jw1 : jw0;
    unsigned short* PB = layer ? PBg1 : PBg0;
    for (int k = ty; k < 128; k += 8) {
      const void* src = (k < 64) ? mw : jw;
      int ab = k & 63;
      size_t idx = (size_t)ab * FG + (size_t)f * G + g0 + tx;
      shbuf[k * 33 + tx] = fp32 ? f2bf(((const float*)src)[idx])
                                : ((const unsigned short*)src)[idx];
    }
    __syncthreads();
    int kk = threadIdx.x & 127, gs = threadIdx.x >> 7;
    for (int gg = gs; gg < 32; gg += 2)
      PB[((size_t)(g0 + gg) * F + f) * 128 + kk] = shbuf[kk * 33 + gg];
    return;
  }

  // ---- transpose_in: x[4096][1024] -> Xt0[1024][4096] ----
  {
    int fp32 = detect_fp32_block(xa, &scnt);
    int tblk = blk - 1249;          // [0,4096)
    int c0 = (tblk & 31) * 32, r0 = (tblk >> 5) * 32;
    const int R = 4096, C = 1024;
    if (fp32) {
#pragma unroll
      for (int i = 0; i < 32; i += 8)
        shbuf[(ty + i) * 33 + tx] =
            f2bf(((const float*)xa)[(size_t)(r0 + ty + i) * C + (c0 + tx)]);
    } else {
#pragma unroll
      for (int i = 0; i < 32; i += 8)
        shbuf[(ty + i) * 33 + tx] = xa[(size_t)(r0 + ty + i) * C + (c0 + tx)];
    }
    __syncthreads();
#pragma unroll
    for (int i = 0; i < 32; i += 8)
      Xt0[(size_t)(c0 + ty + i) * R + (r0 + tx)] = shbuf[tx * 33 + ty + i];
  }
}

// MFMA core: acc[64m x (16*NT)g] += A[64m x K] * Wt[g x K]^T (W pre-offset).
// A fragment: lane holds A[m=lane&15][k=(lane>>4)*8+j]   (16B load)
// B fragment: lane holds Wt[n=lane&15][k=(lane>>4)*8+j]  (16B load)
template <int F, int NT>
__device__ __forceinline__ void mfma_tile(
    const unsigned short* __restrict__ A, const unsigned short* __restrict__ W,
    floatx4 acc[NT], int wave, int n, int q) {
  const unsigned short* a_ptr = A + ((size_t)(wave * 16 + n)) * F + q * 8;
  const unsigned short* w_ptr = W + (size_t)n * F + q * 8;
#pragma unroll
  for (int kk = 0; kk < F; kk += 32) {
    short8 av = *(const short8*)(a_ptr + kk);
#pragma unroll
    for (int t = 0; t < NT; ++t) {
      short8 bv = *(const short8*)(w_ptr + (size_t)t * 16 * F + kk);
      acc[t] = __builtin_amdgcn_mfma_f32_16x16x32_bf16(av, bv, acc[t], 0, 0, 0);
    }
  }
}

// Prep GEMM: Wall[slot][gf] = sum_k L[slot][k]*PBg[gf][k]. Direct store.
__global__ __launch_bounds__(256) void prep_gemm2(
    const unsigned short* __restrict__ L,
    const unsigned short* __restrict__ PBg0,
    const unsigned short* __restrict__ PBg1,
    unsigned short* __restrict__ Wall0, unsigned short* __restrict__ Wall1) {
  int layer = blockIdx.z;
  int GF = layer ? 16384 : 8192;
  int n0 = blockIdx.x * 128;
  if (n0 >= GF) return;
  int m0 = blockIdx.y * 64;
  const unsigned short* PB = layer ? PBg1 : PBg0;
  unsigned short* Wall = layer ? Wall1 : Wall0;
  int wave = threadIdx.x >> 6, lane = threadIdx.x & 63;
  int n = lane & 15, q = lane >> 4;
  floatx4 acc[8];
#pragma unroll
  for (int t = 0; t < 8; ++t) acc[t] = (floatx4){0.f, 0.f, 0.f, 0.f};
  mfma_tile<128, 8>(L + (size_t)m0 * 128, PB + (size_t)n0 * 128, acc, wave, n, q);
#pragma unroll
  for (int t = 0; t < 8; ++t) {
    int gcol = n0 + t * 16 + n;
#pragma unroll
    for (int r = 0; r < 4; ++r) {
      int m = m0 + wave * 16 + q * 4 + r;  // C/D: row=(lane>>4)*4+reg
      Wall[(size_t)m * GF + gcol] = f2bf(acc[t][r]);
    }
  }
}

// Correction matmuls: grid (576, 2); gs = g-half. Raw bf16 stores.
//   bid <256 : V[a][y] = X[24+a, y]      * AS[a][py(y)]
//   bid <512 : U[b][x] = X[x, 24+b]      * SB[px(x)][b]
//   else     : T[a][b] = X[24+a, 24+b]   * mw[a][b]
template <int F>
__global__ __launch_bounds__(256) void corr_gemm(
    const unsigned short* __restrict__ Xt, const unsigned short* __restrict__ Wall,
    unsigned short* __restrict__ V, unsigned short* __restrict__ U,
    unsigned short* __restrict__ T) {
  int bid = blockIdx.x, gs = blockIdx.y;
  int wave = threadIdx.x >> 6, lane = threadIdx.x & 63;
  int n = lane & 15, q = lane >> 4;
  int ipos, slot;
  unsigned short* out;
  if (bid < 256) {
    int a = bid >> 5, y = bid & 31;
    int py = y > 24 ? y - 24 : 0;
    ipos = (24 + a) * 32 + y;
    slot = SLOT_AS + a * 8 + py;
    out = V + (size_t)(a * 32 + y) * 8192;
  } else if (bid < 512) {
    int i = bid - 256;
    int b = i >> 5, x = i & 31;
    int px = x > 24 ? x - 24 : 0;
    ipos = x * 32 + 24 + b;
    slot = SLOT_SB + px * 8 + b;
    out = U + (size_t)(b * 32 + x) * 8192;
  } else {
    int i = bid - 512;
    int a = i >> 3, b = i & 7;
    ipos = (24 + a) * 32 + 24 + b;
    slot = SLOT_M + a * 8 + b;
    out = T + (size_t)(a * 8 + b) * 8192;
  }
  floatx4 acc[4];
#pragma unroll
  for (int t = 0; t < 4; ++t) acc[t] = (floatx4){0.f, 0.f, 0.f, 0.f};
  mfma_tile<F, 4>(Xt + (size_t)ipos * 64 * F,
                  Wall + ((size_t)slot * 128 + gs * 64) * F, acc, wave, n, q);
#pragma unroll
  for (int t = 0; t < 4; ++t) {
    int gcol = gs * 64 + t * 16 + n;
#pragma unroll
    for (int r = 0; r < 4; ++r) {
      int m = wave * 16 + q * 4 + r;
      out[(size_t)m * 128 + gcol] = f2bf(acc[t][r]);
    }
  }
}

// In-place prefix scans (bf16 storage, fp32 accumulate):
// [0,1024) P3 over V (a); [1024,2048) P2 over U (b); [2048,2080) 2D over T.
__global__ __launch_bounds__(256) void scan_corr(unsigned short* __restrict__ V,
                                                 unsigned short* __restrict__ U,
                                                 unsigned short* __restrict__ T) {
  int b = blockIdx.x;
  if (b < 2048) {
    unsigned short* base = (b < 1024) ? V : U;
    int tid = ((b & 1023) * 256 + threadIdx.x);  // (y|x, mg): 262144
    unsigned short* p = base + (size_t)tid;      // stride 262144 over a|b
    float s = 0.f;
#pragma unroll
    for (int a = 0; a < 8; ++a) {
      s += bf2f(p[(size_t)a * 262144]);
      p[(size_t)a * 262144] = f2bf(s);
    }
  } else {
    int mg = (b - 2048) * 256 + threadIdx.x;  // 8192
    float col[8];
#pragma unroll
    for (int i = 0; i < 8; ++i) col[i] = 0.f;
#pragma unroll
    for (int a = 0; a < 8; ++a) {
      float rs = 0.f;
#pragma unroll
      for (int bb = 0; bb < 8; ++bb) {
        size_t idx = (size_t)(a * 8 + bb) * 8192 + mg;
        col[bb] += bf2f(T[idx]);
        rs += col[bb];
        T[idx] = f2bf(rs);
      }
    }
  }
}

// term1 + <=3 prescanned correction tiles + bias + leaky-relu -> bf16.
// grid (1024, 2); gs = g-half. Correction/bias loads hoisted before MFMA.
template <int F>
__global__ __launch_bounds__(256) void final_gemm(
    const unsigned short* __restrict__ Xt, const unsigned short* __restrict__ Wall,
    const unsigned short* __restrict__ V, const unsigned short* __restrict__ U,
    const unsigned short* __restrict__ T, const float* __restrict__ bias,
    unsigned short* __restrict__ Out) {
  int pos = blockIdx.x, gs = blockIdx.y;
  int x = pos >> 5, y = pos & 31;
  int wave = threadIdx.x >> 6, lane = threadIdx.x & 63;
  int n = lane & 15, q = lane >> 4;
  int clsx = x < 7 ? x : (x <= 24 ? 7 : x - 17);
  int clsy = y < 7 ? y : (y <= 24 ? 7 : y - 17);
  int px = x > 24 ? x - 24 : 0;
  int py = y > 24 ? y - 24 : 0;
  const unsigned short* c3 = px ? V + ((size_t)(px - 1) * 32 + y) * 8192 : nullptr;
  const unsigned short* c2 = py ? U + ((size_t)(py - 1) * 32 + x) * 8192 : nullptr;
  const unsigned short* c4 =
      (px && py) ? T + (size_t)((px - 1) * 8 + (py - 1)) * 8192 : nullptr;

  // Hoisted bias + correction sum (loads overlap the MFMA-loop loads).
  float csum[4][4];
#pragma unroll
  for (int t = 0; t < 4; ++t) {
    int gcol = gs * 64 + t * 16 + n;
    float bv = bias[gcol];
#pragma unroll
    for (int r = 0; r < 4; ++r) {
      int m = wave * 16 + q * 4 + r;
      size_t idx = (size_t)m * 128 + gcol;
      float v = bv;
      if (c3) v += bf2f(c3[idx]);
      if (c2) v += bf2f(c2[idx]);
      if (c4) v += bf2f(c4[idx]);
      csum[t][r] = v;
    }
  }

  floatx4 acc[4];
#pragma unroll
  for (int t = 0; t < 4; ++t) acc[t] = (floatx4){0.f, 0.f, 0.f, 0.f};
  mfma_tile<F, 4>(Xt + (size_t)pos * 64 * F,
                  Wall + ((size_t)(SLOT_W1 + clsx * 15 + clsy) * 128 + gs * 64) * F,
                  acc, wave, n, q);

  unsigned short* o = Out + (size_t)pos * 64 * 128;
#pragma unroll
  for (int t = 0; t < 4; ++t) {
    int gcol = gs * 64 + t * 16 + n;
#pragma unroll
    for (int r = 0; r < 4; ++r) {
      int m = wave * 16 + q * 4 + r;  // C/D layout: row=(lane>>4)*4+reg
      float v = acc[t][r] + csum[t][r];
      v = v > 0.f ? v : 0.01f * v;
      o[(size_t)m * 128 + gcol] = f2bf(v);
    }
  }
}

// Transpose Out2[1024][8192] -> d_out [m][g][pos]; dst fp32|bf16 inline det.
__global__ __launch_bounds__(256) void transpose_out(
    const unsigned short* __restrict__ xa, const unsigned short* __restrict__ src,
    unsigned short* __restrict__ d16, float* __restrict__ d32) {
  __shared__ unsigned short tile[32][33];
  __shared__ int scnt;
  int fp32 = detect_fp32_block(xa, &scnt);
  const int R = 1024, C = 8192;
  int tx = threadIdx.x & 31, ty = threadIdx.x >> 5;
  int c0 = blockIdx.x * 32, r0 = blockIdx.y * 32;
#pragma unroll
  for (int i = 0; i < 32; i += 8)
    tile[ty + i][tx] = src[(size_t)(r0 + ty + i) * C + (c0 + tx)];
  __syncthreads();
  if (fp32) {
#pragma unroll
    for (int i = 0; i < 32; i += 8)
      d32[(size_t)(c0 + ty + i) * R + (r0 + tx)] = bf2f(tile[tx][ty + i]);
  } else {
#pragma unroll
    for (int i = 0; i < 32; i += 8)
      d16[(size_t)(c0 + ty + i) * R + (r0 + tx)] = tile[tx][ty + i];
  }
}

extern "C" void kernel_launch(void* const* d_in, const int* in_sizes, int n_in,
                              void* d_out, int out_size, void* d_ws,
                              size_t ws_size, hipStream_t stream) {
  const void* x   = d_in[0];
  const void* mw0 = d_in[5];
  const void* mb0 = d_in[6];
  const void* jw0 = d_in[7];
  const void* jb0 = d_in[8];
  const void* mw1 = d_in[9];
  const void* mb1 = d_in[10];
  const void* jw1 = d_in[11];
  const void* jb1 = d_in[12];

  char* ws = (char*)d_ws;
  const size_t MB = 1u << 20;
  unsigned short* Xt0   = (unsigned short*)(ws + 0);        // 8.4 MB
  unsigned short* A1    = (unsigned short*)(ws + 9 * MB);   // 16.8 MB
  unsigned short* Wall0 = (unsigned short*)(ws + 26 * MB);  // 7.4 MB (448)
  unsigned short* Wall1 = (unsigned short*)(ws + 34 * MB);  // 14.7 MB (448)
  unsigned short* Out2  = (unsigned short*)(ws + 49 * MB);  // 16.8 MB
  unsigned short* PBg0  = (unsigned short*)(ws + 66 * MB);  // 2.1 MB
  unsigned short* PBg1  = (unsigned short*)(ws + 69 * MB);  // 4.2 MB
  unsigned short* L     = (unsigned short*)(ws + 74 * MB);  // 114 KB
  float* bias0 = (float*)(ws + 75 * MB);
  float* bias1 = bias0 + 128;
  unsigned short* V = (unsigned short*)(ws + 76 * MB);      // 4.2 MB
  unsigned short* U = (unsigned short*)(ws + 81 * MB);      // 4.2 MB
  unsigned short* T = (unsigned short*)(ws + 86 * MB);      // 1.05 MB

  mega_setup<<<5345, 256, 0, stream>>>(
      (const unsigned short*)x, mw0, jw0, mw1, jw1, mb0, jb0, mb1, jb1, L,
      bias0, bias1, PBg0, PBg1, Xt0);
  prep_gemm2<<<dim3(128, 7, 2), 256, 0, stream>>>(L, PBg0, PBg1, Wall0, Wall1);

  // ---- Layer 1 (F=64) ----
  corr_gemm<64><<<dim3(576, 2), 256, 0, stream>>>(Xt0, Wall0, V, U, T);
  scan_corr<<<2080, 256, 0, stream>>>(V, U, T);
  final_gemm<64><<<dim3(1024, 2), 256, 0, stream>>>(Xt0, Wall0, V, U, T,
                                                    bias0, A1);
  // ---- Layer 2 (F=128) ----
  corr_gemm<128><<<dim3(576, 2), 256, 0, stream>>>(A1, Wall1, V, U, T);
  scan_corr<<<2080, 256, 0, stream>>>(V, U, T);
  final_gemm<128><<<dim3(1024, 2), 256, 0, stream>>>(A1, Wall1, V, U, T,
                                                     bias1, Out2);

  // Out2 [pos=1024][m*128+g=8192] -> d_out [m][g][pos]
  transpose_out<<<dim3(256, 32), 256, 0, stream>>>(
      (const unsigned short*)x, Out2, (unsigned short*)d_out, (float*)d_out);
}

// Round 11
// 256.911 us; speedup vs baseline: 1.0510x; 1.0033x over previous
//
#include <hip/hip_runtime.h>
#include <stdint.h>

// ---------------------------------------------------------------------------
// LatticeCNN on MI355X — round 11.
//
// Math (validated rounds 2-10):
//   out(x,y) = leaky( X[x,y]·W1[clsx][clsy] + P2 + P3 + S4 + bias )
//   P3[a][y] = prefix_a of X[24+a,y]·AS[a][py]        (V, prescanned)
//   P2[b][x] = prefix_b of X[x,24+b]·SB[px][b]        (U, prescanned)
//   Ta[a][b] = prefix_a of X[24+a,24+b]·mw[a][b]      (T, prescanned over a)
//   S4 = sum_{b<py} Ta[px-1][b]                       (<=7 tile reads, corners)
//   Wall[slot][gf] = sum_k L[slot][k]·PBg[gf][k], K=128=[mw;jw], L closed-form.
//
// Round-10 post-mortem: 9-dispatch chain ~ even with r8's 11 (noise +-8us);
// residual = ~50us harness d_ws poison fills (immovable) + 9x~7us dispatch
// overhead + kernel floors. Round-11: corr and scan merged — corr blocks
// keyed by y|x|b iterate their 8 prefix tiles sequentially accumulating in
// AGPRs (MFMA accumulation IS the scan), storing running sums. 7 dispatches.
//
// Workspace (~88MB of 256MB):
//   Xt0@0 (8.4) | A1@9 (16.8) | Wall0@26 (7.4) | Wall1@34 (14.7)
//   Out2@49 (16.8) | PBg0@66 (2.1) | PBg1@69 (4.2) | L@74 | bias@75
//   V@76 (4.2) | U@81 (4.2) | T@86 (1.05)   (bf16, prescanned)
// ---------------------------------------------------------------------------

typedef __attribute__((ext_vector_type(8))) short short8;
typedef __attribute__((ext_vector_type(4))) float floatx4;

__device__ __forceinline__ float bf2f(unsigned short u) {
  union { uint32_t u; float f; } c; c.u = ((uint32_t)u) << 16; return c.f;
}
__device__ __forceinline__ unsigned short f2bf(float f) {
  union { float f; uint32_t u; } c; c.f = f;
  uint32_t u = c.u;
  uint32_t r = (u + 0x7FFFu + ((u >> 16) & 1u)) >> 16;
  return (unsigned short)r;
}

// Per-block dtype detect: 1 = fp32, 0 = bf16 (x's first 256 u16 exponents).
__device__ __forceinline__ int detect_fp32_block(
    const unsigned short* __restrict__ xa, int* scnt) {
  if (threadIdx.x == 0) *scnt = 0;
  __syncthreads();
  unsigned short v = xa[threadIdx.x & 255];
  int e = (v >> 7) & 0xFF;
  int ok = (v == 0) || (e >= 110 && e <= 140);
  atomicAdd(scnt, ok);
  __syncthreads();
  return (*scnt >= 240) ? 0 : 1;
}

// Weight slot bases inside Wall [slot][G][F]
#define SLOT_W1 0    // 225 combined pointwise slots (clsx*15+clsy)
#define SLOT_SB 225  // 64 slots (px*8+b)
#define SLOT_AS 289  // 64 slots (a*8+py)
#define SLOT_M  353  // 64 slots (a*8+b)
#define N_SLOTS 417
#define N_SLOTS_PAD 448

// Mega setup dispatch (1D, 5345 blocks of 256):
//   [0,224)    : L[448][128] closed-form coefficient matrix
//   224        : bias build (inline detect)
//   [225,1249) : pack mw||jw -> PBg[g*F+f][128] (inline detect)
//   [1249,5345): transpose_in x[4096][1024] -> Xt0[pos][m][f] (inline detect)
__global__ __launch_bounds__(256) void mega_setup(
    const unsigned short* __restrict__ xa,
    const void* __restrict__ mw0, const void* __restrict__ jw0,
    const void* __restrict__ mw1, const void* __restrict__ jw1,
    const void* __restrict__ mb0, const void* __restrict__ jb0,
    const void* __restrict__ mb1, const void* __restrict__ jb1,
    unsigned short* __restrict__ L, float* __restrict__ bias0,
    float* __restrict__ bias1, unsigned short* __restrict__ PBg0,
    unsigned short* __restrict__ PBg1, unsigned short* __restrict__ Xt0) {
  __shared__ unsigned short shbuf[128 * 33];
  __shared__ int scnt;
  int blk = blockIdx.x;

  if (blk < 224) {  // ---- L build ----
    int tid = blk * 256 + threadIdx.x;  // 448*128 entries
    int slot = tid >> 7, k = tid & 127;
    int isj = k >= 64, ab = k & 63, a = ab >> 3, b = ab & 7;
    float v = 0.f;
    if (slot < 225) {
      int cx = slot / 15, cy = slot % 15;
      int pmx = cx < 7 ? cx : 7, pxx = cx > 7 ? cx - 7 : 0;
      int pmy = cy < 7 ? cy : 7, pyy = cy > 7 ? cy - 7 : 0;
      if (!isj) v = (a >= pxx && b >= pyy) ? 0.5f : 0.f;
      else      v = (a <= pmx && b <= pmy) ? 0.5f : 0.f;
    } else if (slot < 289) {
      int s = slot - SLOT_SB, px = s >> 3, b0 = s & 7;
      if (!isj) v = (a >= px && b == b0) ? 0.5f : 0.f;
    } else if (slot < 353) {
      int s = slot - SLOT_AS, a0 = s >> 3, py = s & 7;
      if (!isj) v = (a == a0 && b >= py) ? 0.5f : 0.f;
    } else if (slot < 417) {
      int s = slot - SLOT_M, a0 = s >> 3, b0 = s & 7;
      if (!isj) v = (a == a0 && b == b0) ? 0.5f : 0.f;
    }
    L[tid] = f2bf(v);
    return;
  }

  if (blk == 224) {  // ---- bias ----
    int fp32 = detect_fp32_block(xa, &scnt);
    int g = threadIdx.x & 127;
    const void* mb = (threadIdx.x < 128) ? mb0 : mb1;
    const void* jb = (threadIdx.x < 128) ? jb0 : jb1;
    float* bo = (threadIdx.x < 128) ? bias0 : bias1;
    float m = fp32 ? ((const float*)mb)[g] : bf2f(((const unsigned short*)mb)[g]);
    float j = fp32 ? ((const float*)jb)[g] : bf2f(((const unsigned short*)jb)[g]);
    bo[g] = 0.5f * (m + j);
    return;
  }

  int tx = threadIdx.x & 31, ty = threadIdx.x >> 5;  // (32,8) view

  if (blk < 1249) {  // ---- pack weights: gf-order, K=128 ----
    int fp32 = detect_fp32_block(xa, &scnt);
    int pblk = blk - 225;           // [0,1024)
    int layer = pblk >> 9;          // 512 per layer
    int rem = pblk & 511;
    int f = rem >> 2, gt = rem & 3;
    int F = layer ? 128 : 64;
    if (f >= F) return;
    int g0 = gt * 32;
    const int G = 128, FG = F * G;
    const void* mw = layer ? mw1 : mw0;
    const void* jw = layer ? jw1 : jw0;
    unsigned short* PB = layer ? PBg1 : PBg0;
    for (int k = ty; k < 128; k += 8) {
      const void* src = (k < 64) ? mw : jw;
      int ab = k & 63;
      size_t idx = (size_t)ab * FG + (size_t)f * G + g0 + tx;
      shbuf[k * 33 + tx] = fp32 ? f2bf(((const float*)src)[idx])
                                : ((const unsigned short*)src)[idx];
    }
    __syncthreads();
    int kk = threadIdx.x & 127, gs = threadIdx.x >> 7;
    for (int gg = gs; gg < 32; gg += 2)
      PB[((size_t)(g0 + gg) * F + f) * 128 + kk] = shbuf[kk * 33 + gg];
    return;
  }

  // ---- transpose_in: x[4096][1024] -> Xt0[1024][4096] ----
  {
    int fp32 = detect_fp32_block(xa, &scnt);
    int tblk = blk - 1249;          // [0,4096)
    int c0 = (tblk & 31) * 32, r0 = (tblk >> 5) * 32;
    const int R = 4096, C = 1024;
    if (fp32) {
#pragma unroll
      for (int i = 0; i < 32; i += 8)
        shbuf[(ty + i) * 33 + tx] =
            f2bf(((const float*)xa)[(size_t)(r0 + ty + i) * C + (c0 + tx)]);
    } else {
#pragma unroll
      for (int i = 0; i < 32; i += 8)
        shbuf[(ty + i) * 33 + tx] = xa[(size_t)(r0 + ty + i) * C + (c0 + tx)];
    }
    __syncthreads();
#pragma unroll
    for (int i = 0; i < 32; i += 8)
      Xt0[(size_t)(c0 + ty + i) * R + (r0 + tx)] = shbuf[tx * 33 + ty + i];
  }
}

// MFMA core: acc[64m x (16*NT)g] += A[64m x K] * Wt[g x K]^T (W pre-offset).
// A fragment: lane holds A[m=lane&15][k=(lane>>4)*8+j]   (16B load)
// B fragment: lane holds Wt[n=lane&15][k=(lane>>4)*8+j]  (16B load)
template <int F, int NT>
__device__ __forceinline__ void mfma_tile(
    const unsigned short* __restrict__ A, const unsigned short* __restrict__ W,
    floatx4 acc[NT], int wave, int n, int q) {
  const unsigned short* a_ptr = A + ((size_t)(wave * 16 + n)) * F + q * 8;
  const unsigned short* w_ptr = W + (size_t)n * F + q * 8;
#pragma unroll
  for (int kk = 0; kk < F; kk += 32) {
    short8 av = *(const short8*)(a_ptr + kk);
#pragma unroll
    for (int t = 0; t < NT; ++t) {
      short8 bv = *(const short8*)(w_ptr + (size_t)t * 16 * F + kk);
      acc[t] = __builtin_amdgcn_mfma_f32_16x16x32_bf16(av, bv, acc[t], 0, 0, 0);
    }
  }
}

// Prep GEMM: Wall[slot][gf] = sum_k L[slot][k]*PBg[gf][k]. Direct store.
__global__ __launch_bounds__(256) void prep_gemm2(
    const unsigned short* __restrict__ L,
    const unsigned short* __restrict__ PBg0,
    const unsigned short* __restrict__ PBg1,
    unsigned short* __restrict__ Wall0, unsigned short* __restrict__ Wall1) {
  int layer = blockIdx.z;
  int GF = layer ? 16384 : 8192;
  int n0 = blockIdx.x * 128;
  if (n0 >= GF) return;
  int m0 = blockIdx.y * 64;
  const unsigned short* PB = layer ? PBg1 : PBg0;
  unsigned short* Wall = layer ? Wall1 : Wall0;
  int wave = threadIdx.x >> 6, lane = threadIdx.x & 63;
  int n = lane & 15, q = lane >> 4;
  floatx4 acc[8];
#pragma unroll
  for (int t = 0; t < 8; ++t) acc[t] = (floatx4){0.f, 0.f, 0.f, 0.f};
  mfma_tile<128, 8>(L + (size_t)m0 * 128, PB + (size_t)n0 * 128, acc, wave, n, q);
#pragma unroll
  for (int t = 0; t < 8; ++t) {
    int gcol = n0 + t * 16 + n;
#pragma unroll
    for (int r = 0; r < 4; ++r) {
      int m = m0 + wave * 16 + q * 4 + r;  // C/D: row=(lane>>4)*4+reg
      Wall[(size_t)m * GF + gcol] = f2bf(acc[t][r]);
    }
  }
}

// Fused correction matmul + prefix scan. grid (72, 2); gs = g-half.
// MFMA accumulation in registers IS the scan; running sums stored bf16.
//   bid <32 : V-block, y=bid:   V[a][y] = prefix_a X[24+a,y]·AS[a][py]
//   bid <64 : U-block, x=bid-32: U[b][x] = prefix_b X[x,24+b]·SB[px][b]
//   else    : T-block, b=bid-64: Ta[a][b] = prefix_a X[24+a,24+b]·mw[a][b]
template <int F>
__global__ __launch_bounds__(256) void corr_scan(
    const unsigned short* __restrict__ Xt, const unsigned short* __restrict__ Wall,
    unsigned short* __restrict__ V, unsigned short* __restrict__ U,
    unsigned short* __restrict__ T) {
  int bid = blockIdx.x, gs = blockIdx.y;
  int wave = threadIdx.x >> 6, lane = threadIdx.x & 63;
  int n = lane & 15, q = lane >> 4;
  floatx4 acc[4];
#pragma unroll
  for (int t = 0; t < 4; ++t) acc[t] = (floatx4){0.f, 0.f, 0.f, 0.f};

  for (int i = 0; i < 8; ++i) {
    int ipos, slot;
    unsigned short* out;
    if (bid < 32) {
      int y = bid, py = y > 24 ? y - 24 : 0;
      ipos = (24 + i) * 32 + y;
      slot = SLOT_AS + i * 8 + py;
      out = V + (size_t)(i * 32 + y) * 8192;
    } else if (bid < 64) {
      int x = bid - 32, px = x > 24 ? x - 24 : 0;
      ipos = x * 32 + 24 + i;
      slot = SLOT_SB + px * 8 + i;
      out = U + (size_t)(i * 32 + x) * 8192;
    } else {
      int b = bid - 64;
      ipos = (24 + i) * 32 + 24 + b;
      slot = SLOT_M + i * 8 + b;
      out = T + (size_t)(i * 8 + b) * 8192;
    }
    mfma_tile<F, 4>(Xt + (size_t)ipos * 64 * F,
                    Wall + ((size_t)slot * 128 + gs * 64) * F, acc, wave, n, q);
#pragma unroll
    for (int t = 0; t < 4; ++t) {
      int gcol = gs * 64 + t * 16 + n;
#pragma unroll
      for (int r = 0; r < 4; ++r) {
        int m = wave * 16 + q * 4 + r;
        out[(size_t)m * 128 + gcol] = f2bf(acc[t][r]);
      }
    }
  }
}

// term1 + prescanned corrections (V,U direct; T summed over b<py) + bias +
// leaky-relu -> bf16 [pos][m][128]. grid (1024, 2).
template <int F>
__global__ __launch_bounds__(256) void final_gemm(
    const unsigned short* __restrict__ Xt, const unsigned short* __restrict__ Wall,
    const unsigned short* __restrict__ V, const unsigned short* __restrict__ U,
    const unsigned short* __restrict__ T, const float* __restrict__ bias,
    unsigned short* __restrict__ Out) {
  int pos = blockIdx.x, gs = blockIdx.y;
  int x = pos >> 5, y = pos & 31;
  int wave = threadIdx.x >> 6, lane = threadIdx.x & 63;
  int n = lane & 15, q = lane >> 4;
  int clsx = x < 7 ? x : (x <= 24 ? 7 : x - 17);
  int clsy = y < 7 ? y : (y <= 24 ? 7 : y - 17);
  int px = x > 24 ? x - 24 : 0;
  int py = y > 24 ? y - 24 : 0;
  const unsigned short* c3 = px ? V + ((size_t)(px - 1) * 32 + y) * 8192 : nullptr;
  const unsigned short* c2 = py ? U + ((size_t)(py - 1) * 32 + x) * 8192 : nullptr;

  // Hoisted bias + correction sums (loads overlap the MFMA-loop loads).
  float csum[4][4];
#pragma unroll
  for (int t = 0; t < 4; ++t) {
    int gcol = gs * 64 + t * 16 + n;
    float bv = bias[gcol];
#pragma unroll
    for (int r = 0; r < 4; ++r) {
      int m = wave * 16 + q * 4 + r;
      size_t idx = (size_t)m * 128 + gcol;
      float v = bv;
      if (c3) v += bf2f(c3[idx]);
      if (c2) v += bf2f(c2[idx]);
      csum[t][r] = v;
    }
  }
  if (px) {
    for (int b = 0; b < py; ++b) {
      const unsigned short* c4 = T + (size_t)((px - 1) * 8 + b) * 8192;
#pragma unroll
      for (int t = 0; t < 4; ++t) {
        int gcol = gs * 64 + t * 16 + n;
#pragma unroll
        for (int r = 0; r < 4; ++r) {
          int m = wave * 16 + q * 4 + r;
          csum[t][r] += bf2f(c4[(size_t)m * 128 + gcol]);
        }
      }
    }
  }

  floatx4 acc[4];
#pragma unroll
  for (int t = 0; t < 4; ++t) acc[t] = (floatx4){0.f, 0.f, 0.f, 0.f};
  mfma_tile<F, 4>(Xt + (size_t)pos * 64 * F,
                  Wall + ((size_t)(SLOT_W1 + clsx * 15 + clsy) * 128 + gs * 64) * F,
                  acc, wave, n, q);

  unsigned short* o = Out + (size_t)pos * 64 * 128;
#pragma unroll
  for (int t = 0; t < 4; ++t) {
    int gcol = gs * 64 + t * 16 + n;
#pragma unroll
    for (int r = 0; r < 4; ++r) {
      int m = wave * 16 + q * 4 + r;  // C/D layout: row=(lane>>4)*4+reg
      float v = acc[t][r] + csum[t][r];
      v = v > 0.f ? v : 0.01f * v;
      o[(size_t)m * 128 + gcol] = f2bf(v);
    }
  }
}

// Transpose Out2[1024][8192] -> d_out [m][g][pos]; dst fp32|bf16 inline det.
__global__ __launch_bounds__(256) void transpose_out(
    const unsigned short* __restrict__ xa, const unsigned short* __restrict__ src,
    unsigned short* __restrict__ d16, float* __restrict__ d32) {
  __shared__ unsigned short tile[32][33];
  __shared__ int scnt;
  int fp32 = detect_fp32_block(xa, &scnt);
  const int R = 1024, C = 8192;
  int tx = threadIdx.x & 31, ty = threadIdx.x >> 5;
  int c0 = blockIdx.x * 32, r0 = blockIdx.y * 32;
#pragma unroll
  for (int i = 0; i < 32; i += 8)
    tile[ty + i][tx] = src[(size_t)(r0 + ty + i) * C + (c0 + tx)];
  __syncthreads();
  if (fp32) {
#pragma unroll
    for (int i = 0; i < 32; i += 8)
      d32[(size_t)(c0 + ty + i) * R + (r0 + tx)] = bf2f(tile[tx][ty + i]);
  } else {
#pragma unroll
    for (int i = 0; i < 32; i += 8)
      d16[(size_t)(c0 + ty + i) * R + (r0 + tx)] = tile[tx][ty + i];
  }
}

extern "C" void kernel_launch(void* const* d_in, const int* in_sizes, int n_in,
                              void* d_out, int out_size, void* d_ws,
                              size_t ws_size, hipStream_t stream) {
  const void* x   = d_in[0];
  const void* mw0 = d_in[5];
  const void* mb0 = d_in[6];
  const void* jw0 = d_in[7];
  const void* jb0 = d_in[8];
  const void* mw1 = d_in[9];
  const void* mb1 = d_in[10];
  const void* jw1 = d_in[11];
  const void* jb1 = d_in[12];

  char* ws = (char*)d_ws;
  const size_t MB = 1u << 20;
  unsigned short* Xt0   = (unsigned short*)(ws + 0);        // 8.4 MB
  unsigned short* A1    = (unsigned short*)(ws + 9 * MB);   // 16.8 MB
  unsigned short* Wall0 = (unsigned short*)(ws + 26 * MB);  // 7.4 MB (448)
  unsigned short* Wall1 = (unsigned short*)(ws + 34 * MB);  // 14.7 MB (448)
  unsigned short* Out2  = (unsigned short*)(ws + 49 * MB);  // 16.8 MB
  unsigned short* PBg0  = (unsigned short*)(ws + 66 * MB);  // 2.1 MB
  unsigned short* PBg1  = (unsigned short*)(ws + 69 * MB);  // 4.2 MB
  unsigned short* L     = (unsigned short*)(ws + 74 * MB);  // 114 KB
  float* bias0 = (float*)(ws + 75 * MB);
  float* bias1 = bias0 + 128;
  unsigned short* V = (unsigned short*)(ws + 76 * MB);      // 4.2 MB
  unsigned short* U = (unsigned short*)(ws + 81 * MB);      // 4.2 MB
  unsigned short* T = (unsigned short*)(ws + 86 * MB);      // 1.05 MB

  mega_setup<<<5345, 256, 0, stream>>>(
      (const unsigned short*)x, mw0, jw0, mw1, jw1, mb0, jb0, mb1, jb1, L,
      bias0, bias1, PBg0, PBg1, Xt0);
  prep_gemm2<<<dim3(128, 7, 2), 256, 0, stream>>>(L, PBg0, PBg1, Wall0, Wall1);

  // ---- Layer 1 (F=64) ----
  corr_scan<64><<<dim3(72, 2), 256, 0, stream>>>(Xt0, Wall0, V, U, T);
  final_gemm<64><<<dim3(1024, 2), 256, 0, stream>>>(Xt0, Wall0, V, U, T,
                                                    bias0, A1);
  // ---- Layer 2 (F=128) ----
  corr_scan<128><<<dim3(72, 2), 256, 0, stream>>>(A1, Wall1, V, U, T);
  final_gemm<128><<<dim3(1024, 2), 256, 0, stream>>>(A1, Wall1, V, U, T,
                                                     bias1, Out2);

  // Out2 [pos=1024][m*128+g=8192] -> d_out [m][g][pos]
  transpose_out<<<dim3(256, 32), 256, 0, stream>>>(
      (const unsigned short*)x, Out2, (unsigned short*)d_out, (float*)d_out);
}

// Round 12
// 256.032 us; speedup vs baseline: 1.0546x; 1.0034x over previous
//
#include <hip/hip_runtime.h>
#include <stdint.h>

// ---------------------------------------------------------------------------
// LatticeCNN on MI355X — round 12.
//
// Math (validated rounds 2-11):
//   out(x,y) = leaky( X[x,y]·W1[clsx][clsy] + P2 + P3 + S4 + bias )
//   P3[a][y] = prefix_a of X[24+a,y]·AS[a][py]        (V, prescanned)
//   P2[b][x] = prefix_b of X[x,24+b]·SB[px][b]        (U, prescanned)
//   Ta[a][b] = prefix_a of X[24+a,24+b]·mw[a][b]      (T, prescanned over a)
//   S4 = sum_{b<py} Ta[px-1][b]                       (<=7 tile reads, corners)
//   Wall[slot][gf] = sum_k L[slot][k]·PBg[gf][k], K=128=[mw;jw], L closed-form.
//
// Round-11 post-mortem: fused corr_scan was NEUTRAL — it removed 2 gaps +
// scan traffic but collapsed parallelism to 144 blocks (0.56/CU, 8-iter
// serial MFMA chain) costing what it saved. Round-12: same fusion, wave-level
// decomposition — each of 72 chains splits into 4 m-quarters x 8 g-16ths =
// 2304 independent wave-units (NT=1, 4-VGPR acc, 9 waves/CU). 7 dispatches.
//
// Workspace (~88MB of 256MB):
//   Xt0@0 (8.4) | A1@9 (16.8) | Wall0@26 (7.4) | Wall1@34 (14.7)
//   Out2@49 (16.8) | PBg0@66 (2.1) | PBg1@69 (4.2) | L@74 | bias@75
//   V@76 (4.2) | U@81 (4.2) | T@86 (1.05)   (bf16, prescanned)
// ---------------------------------------------------------------------------

typedef __attribute__((ext_vector_type(8))) short short8;
typedef __attribute__((ext_vector_type(4))) float floatx4;

__device__ __forceinline__ float bf2f(unsigned short u) {
  union { uint32_t u; float f; } c; c.u = ((uint32_t)u) << 16; return c.f;
}
__device__ __forceinline__ unsigned short f2bf(float f) {
  union { float f; uint32_t u; } c; c.f = f;
  uint32_t u = c.u;
  uint32_t r = (u + 0x7FFFu + ((u >> 16) & 1u)) >> 16;
  return (unsigned short)r;
}

// Per-block dtype detect: 1 = fp32, 0 = bf16 (x's first 256 u16 exponents).
__device__ __forceinline__ int detect_fp32_block(
    const unsigned short* __restrict__ xa, int* scnt) {
  if (threadIdx.x == 0) *scnt = 0;
  __syncthreads();
  unsigned short v = xa[threadIdx.x & 255];
  int e = (v >> 7) & 0xFF;
  int ok = (v == 0) || (e >= 110 && e <= 140);
  atomicAdd(scnt, ok);
  __syncthreads();
  return (*scnt >= 240) ? 0 : 1;
}

// Weight slot bases inside Wall [slot][G][F]
#define SLOT_W1 0    // 225 combined pointwise slots (clsx*15+clsy)
#define SLOT_SB 225  // 64 slots (px*8+b)
#define SLOT_AS 289  // 64 slots (a*8+py)
#define SLOT_M  353  // 64 slots (a*8+b)
#define N_SLOTS 417
#define N_SLOTS_PAD 448

// Mega setup dispatch (1D, 5345 blocks of 256):
//   [0,224)    : L[448][128] closed-form coefficient matrix
//   224        : bias build (inline detect)
//   [225,1249) : pack mw||jw -> PBg[g*F+f][128] (inline detect)
//   [1249,5345): transpose_in x[4096][1024] -> Xt0[pos][m][f] (inline detect)
__global__ __launch_bounds__(256) void mega_setup(
    const unsigned short* __restrict__ xa,
    const void* __restrict__ mw0, const void* __restrict__ jw0,
    const void* __restrict__ mw1, const void* __restrict__ jw1,
    const void* __restrict__ mb0, const void* __restrict__ jb0,
    const void* __restrict__ mb1, const void* __restrict__ jb1,
    unsigned short* __restrict__ L, float* __restrict__ bias0,
    float* __restrict__ bias1, unsigned short* __restrict__ PBg0,
    unsigned short* __restrict__ PBg1, unsigned short* __restrict__ Xt0) {
  __shared__ unsigned short shbuf[128 * 33];
  __shared__ int scnt;
  int blk = blockIdx.x;

  if (blk < 224) {  // ---- L build ----
    int tid = blk * 256 + threadIdx.x;  // 448*128 entries
    int slot = tid >> 7, k = tid & 127;
    int isj = k >= 64, ab = k & 63, a = ab >> 3, b = ab & 7;
    float v = 0.f;
    if (slot < 225) {
      int cx = slot / 15, cy = slot % 15;
      int pmx = cx < 7 ? cx : 7, pxx = cx > 7 ? cx - 7 : 0;
      int pmy = cy < 7 ? cy : 7, pyy = cy > 7 ? cy - 7 : 0;
      if (!isj) v = (a >= pxx && b >= pyy) ? 0.5f : 0.f;
      else      v = (a <= pmx && b <= pmy) ? 0.5f : 0.f;
    } else if (slot < 289) {
      int s = slot - SLOT_SB, px = s >> 3, b0 = s & 7;
      if (!isj) v = (a >= px && b == b0) ? 0.5f : 0.f;
    } else if (slot < 353) {
      int s = slot - SLOT_AS, a0 = s >> 3, py = s & 7;
      if (!isj) v = (a == a0 && b >= py) ? 0.5f : 0.f;
    } else if (slot < 417) {
      int s = slot - SLOT_M, a0 = s >> 3, b0 = s & 7;
      if (!isj) v = (a == a0 && b == b0) ? 0.5f : 0.f;
    }
    L[tid] = f2bf(v);
    return;
  }

  if (blk == 224) {  // ---- bias ----
    int fp32 = detect_fp32_block(xa, &scnt);
    int g = threadIdx.x & 127;
    const void* mb = (threadIdx.x < 128) ? mb0 : mb1;
    const void* jb = (threadIdx.x < 128) ? jb0 : jb1;
    float* bo = (threadIdx.x < 128) ? bias0 : bias1;
    float m = fp32 ? ((const float*)mb)[g] : bf2f(((const unsigned short*)mb)[g]);
    float j = fp32 ? ((const float*)jb)[g] : bf2f(((const unsigned short*)jb)[g]);
    bo[g] = 0.5f * (m + j);
    return;
  }

  int tx = threadIdx.x & 31, ty = threadIdx.x >> 5;  // (32,8) view

  if (blk < 1249) {  // ---- pack weights: gf-order, K=128 ----
    int fp32 = detect_fp32_block(xa, &scnt);
    int pblk = blk - 225;           // [0,1024)
    int layer = pblk >> 9;          // 512 per layer
    int rem = pblk & 511;
    int f = rem >> 2, gt = rem & 3;
    int F = layer ? 128 : 64;
    if (f >= F) return;
    int g0 = gt * 32;
    const int G = 128, FG = F * G;
    const void* mw = layer ? mw1 : mw0;
    const void* jw = layer ? jw1 : jw0;
    unsigned short* PB = layer ? PBg1 : PBg0;
    for (int k = ty; k < 128; k += 8) {
      const void* src = (k < 64) ? mw : jw;
      int ab = k & 63;
      size_t idx = (size_t)ab * FG + (size_t)f * G + g0 + tx;
      shbuf[k * 33 + tx] = fp32 ? f2bf(((const float*)src)[idx])
                                : ((const unsigned short*)src)[idx];
    }
    __syncthreads();
    int kk = threadIdx.x & 127, gs = threadIdx.x >> 7;
    for (int gg = gs; gg < 32; gg += 2)
      PB[((size_t)(g0 + gg) * F + f) * 128 + kk] = shbuf[kk * 33 + gg];
    return;
  }

  // ---- transpose_in: x[4096][1024] -> Xt0[1024][4096] ----
  {
    int fp32 = detect_fp32_block(xa, &scnt);
    int tblk = blk - 1249;          // [0,4096)
    int c0 = (tblk & 31) * 32, r0 = (tblk >> 5) * 32;
    const int R = 4096, C = 1024;
    if (fp32) {
#pragma unroll
      for (int i = 0; i < 32; i += 8)
        shbuf[(ty + i) * 33 + tx] =
            f2bf(((const float*)xa)[(size_t)(r0 + ty + i) * C + (c0 + tx)]);
    } else {
#pragma unroll
      for (int i = 0; i < 32; i += 8)
        shbuf[(ty + i) * 33 + tx] = xa[(size_t)(r0 + ty + i) * C + (c0 + tx)];
    }
    __syncthreads();
#pragma unroll
    for (int i = 0; i < 32; i += 8)
      Xt0[(size_t)(c0 + ty + i) * R + (r0 + tx)] = shbuf[tx * 33 + ty + i];
  }
}

// MFMA core: acc[64m x (16*NT)g] += A[64m x K] * Wt[g x K]^T (W pre-offset).
// A fragment: lane holds A[m=lane&15][k=(lane>>4)*8+j]   (16B load)
// B fragment: lane holds Wt[n=lane&15][k=(lane>>4)*8+j]  (16B load)
template <int F, int NT>
__device__ __forceinline__ void mfma_tile(
    const unsigned short* __restrict__ A, const unsigned short* __restrict__ W,
    floatx4 acc[NT], int wave, int n, int q) {
  const unsigned short* a_ptr = A + ((size_t)(wave * 16 + n)) * F + q * 8;
  const unsigned short* w_ptr = W + (size_t)n * F + q * 8;
#pragma unroll
  for (int kk = 0; kk < F; kk += 32) {
    short8 av = *(const short8*)(a_ptr + kk);
#pragma unroll
    for (int t = 0; t < NT; ++t) {
      short8 bv = *(const short8*)(w_ptr + (size_t)t * 16 * F + kk);
      acc[t] = __builtin_amdgcn_mfma_f32_16x16x32_bf16(av, bv, acc[t], 0, 0, 0);
    }
  }
}

// Prep GEMM: Wall[slot][gf] = sum_k L[slot][k]*PBg[gf][k]. Direct store.
__global__ __launch_bounds__(256) void prep_gemm2(
    const unsigned short* __restrict__ L,
    const unsigned short* __restrict__ PBg0,
    const unsigned short* __restrict__ PBg1,
    unsigned short* __restrict__ Wall0, unsigned short* __restrict__ Wall1) {
  int layer = blockIdx.z;
  int GF = layer ? 16384 : 8192;
  int n0 = blockIdx.x * 128;
  if (n0 >= GF) return;
  int m0 = blockIdx.y * 64;
  const unsigned short* PB = layer ? PBg1 : PBg0;
  unsigned short* Wall = layer ? Wall1 : Wall0;
  int wave = threadIdx.x >> 6, lane = threadIdx.x & 63;
  int n = lane & 15, q = lane >> 4;
  floatx4 acc[8];
#pragma unroll
  for (int t = 0; t < 8; ++t) acc[t] = (floatx4){0.f, 0.f, 0.f, 0.f};
  mfma_tile<128, 8>(L + (size_t)m0 * 128, PB + (size_t)n0 * 128, acc, wave, n, q);
#pragma unroll
  for (int t = 0; t < 8; ++t) {
    int gcol = n0 + t * 16 + n;
#pragma unroll
    for (int r = 0; r < 4; ++r) {
      int m = m0 + wave * 16 + q * 4 + r;  // C/D: row=(lane>>4)*4+reg
      Wall[(size_t)m * GF + gcol] = f2bf(acc[t][r]);
    }
  }
}

// Fused correction matmul + prefix scan, wave-decomposed.
// grid (72 chains, 8 g-16ths); 4 waves = 4 m-quarters. Each WAVE owns a
// 16x16 output tile of one chain and scans its 8 taps with NT=1 register
// accumulation (MFMA accumulation IS the scan). 2304 independent waves.
//   chain <32 : V, y=chain:    V[a][y] = prefix_a X[24+a,y]·AS[a][py]
//   chain <64 : U, x=chain-32: U[b][x] = prefix_b X[x,24+b]·SB[px][b]
//   else      : T, b=chain-64: Ta[a][b] = prefix_a X[24+a,24+b]·mw[a][b]
template <int F>
__global__ __launch_bounds__(256) void corr_scan(
    const unsigned short* __restrict__ Xt, const unsigned short* __restrict__ Wall,
    unsigned short* __restrict__ V, unsigned short* __restrict__ U,
    unsigned short* __restrict__ T) {
  int chain = blockIdx.x, gq = blockIdx.y;
  int mq = threadIdx.x >> 6, lane = threadIdx.x & 63;
  int n = lane & 15, q = lane >> 4;
  floatx4 acc[1];
  acc[0] = (floatx4){0.f, 0.f, 0.f, 0.f};

  for (int i = 0; i < 8; ++i) {
    int ipos, slot;
    unsigned short* out;
    if (chain < 32) {
      int y = chain, py = y > 24 ? y - 24 : 0;
      ipos = (24 + i) * 32 + y;
      slot = SLOT_AS + i * 8 + py;
      out = V + (size_t)(i * 32 + y) * 8192;
    } else if (chain < 64) {
      int x = chain - 32, px = x > 24 ? x - 24 : 0;
      ipos = x * 32 + 24 + i;
      slot = SLOT_SB + px * 8 + i;
      out = U + (size_t)(i * 32 + x) * 8192;
    } else {
      int b = chain - 64;
      ipos = (24 + i) * 32 + 24 + b;
      slot = SLOT_M + i * 8 + b;
      out = T + (size_t)(i * 8 + b) * 8192;
    }
    mfma_tile<F, 1>(Xt + (size_t)ipos * 64 * F,
                    Wall + ((size_t)slot * 128 + gq * 16) * F, acc, mq, n, q);
    int gcol = gq * 16 + n;
#pragma unroll
    for (int r = 0; r < 4; ++r) {
      int m = mq * 16 + q * 4 + r;  // C/D: row=(lane>>4)*4+reg
      out[(size_t)m * 128 + gcol] = f2bf(acc[0][r]);
    }
  }
}

// term1 + prescanned corrections (V,U direct; T summed over b<py) + bias +
// leaky-relu -> bf16 [pos][m][128]. grid (1024, 2).
template <int F>
__global__ __launch_bounds__(256) void final_gemm(
    const unsigned short* __restrict__ Xt, const unsigned short* __restrict__ Wall,
    const unsigned short* __restrict__ V, const unsigned short* __restrict__ U,
    const unsigned short* __restrict__ T, const float* __restrict__ bias,
    unsigned short* __restrict__ Out) {
  int pos = blockIdx.x, gs = blockIdx.y;
  int x = pos >> 5, y = pos & 31;
  int wave = threadIdx.x >> 6, lane = threadIdx.x & 63;
  int n = lane & 15, q = lane >> 4;
  int clsx = x < 7 ? x : (x <= 24 ? 7 : x - 17);
  int clsy = y < 7 ? y : (y <= 24 ? 7 : y - 17);
  int px = x > 24 ? x - 24 : 0;
  int py = y > 24 ? y - 24 : 0;
  const unsigned short* c3 = px ? V + ((size_t)(px - 1) * 32 + y) * 8192 : nullptr;
  const unsigned short* c2 = py ? U + ((size_t)(py - 1) * 32 + x) * 8192 : nullptr;

  // Hoisted bias + correction sums (loads overlap the MFMA-loop loads).
  float csum[4][4];
#pragma unroll
  for (int t = 0; t < 4; ++t) {
    int gcol = gs * 64 + t * 16 + n;
    float bv = bias[gcol];
#pragma unroll
    for (int r = 0; r < 4; ++r) {
      int m = wave * 16 + q * 4 + r;
      size_t idx = (size_t)m * 128 + gcol;
      float v = bv;
      if (c3) v += bf2f(c3[idx]);
      if (c2) v += bf2f(c2[idx]);
      csum[t][r] = v;
    }
  }
  if (px) {
    for (int b = 0; b < py; ++b) {
      const unsigned short* c4 = T + (size_t)((px - 1) * 8 + b) * 8192;
#pragma unroll
      for (int t = 0; t < 4; ++t) {
        int gcol = gs * 64 + t * 16 + n;
#pragma unroll
        for (int r = 0; r < 4; ++r) {
          int m = wave * 16 + q * 4 + r;
          csum[t][r] += bf2f(c4[(size_t)m * 128 + gcol]);
        }
      }
    }
  }

  floatx4 acc[4];
#pragma unroll
  for (int t = 0; t < 4; ++t) acc[t] = (floatx4){0.f, 0.f, 0.f, 0.f};
  mfma_tile<F, 4>(Xt + (size_t)pos * 64 * F,
                  Wall + ((size_t)(SLOT_W1 + clsx * 15 + clsy) * 128 + gs * 64) * F,
                  acc, wave, n, q);

  unsigned short* o = Out + (size_t)pos * 64 * 128;
#pragma unroll
  for (int t = 0; t < 4; ++t) {
    int gcol = gs * 64 + t * 16 + n;
#pragma unroll
    for (int r = 0; r < 4; ++r) {
      int m = wave * 16 + q * 4 + r;  // C/D layout: row=(lane>>4)*4+reg
      float v = acc[t][r] + csum[t][r];
      v = v > 0.f ? v : 0.01f * v;
      o[(size_t)m * 128 + gcol] = f2bf(v);
    }
  }
}

// Transpose Out2[1024][8192] -> d_out [m][g][pos]; dst fp32|bf16 inline det.
__global__ __launch_bounds__(256) void transpose_out(
    const unsigned short* __restrict__ xa, const unsigned short* __restrict__ src,
    unsigned short* __restrict__ d16, float* __restrict__ d32) {
  __shared__ unsigned short tile[32][33];
  __shared__ int scnt;
  int fp32 = detect_fp32_block(xa, &scnt);
  const int R = 1024, C = 8192;
  int tx = threadIdx.x & 31, ty = threadIdx.x >> 5;
  int c0 = blockIdx.x * 32, r0 = blockIdx.y * 32;
#pragma unroll
  for (int i = 0; i < 32; i += 8)
    tile[ty + i][tx] = src[(size_t)(r0 + ty + i) * C + (c0 + tx)];
  __syncthreads();
  if (fp32) {
#pragma unroll
    for (int i = 0; i < 32; i += 8)
      d32[(size_t)(c0 + ty + i) * R + (r0 + tx)] = bf2f(tile[tx][ty + i]);
  } else {
#pragma unroll
    for (int i = 0; i < 32; i += 8)
      d16[(size_t)(c0 + ty + i) * R + (r0 + tx)] = tile[tx][ty + i];
  }
}

extern "C" void kernel_launch(void* const* d_in, const int* in_sizes, int n_in,
                              void* d_out, int out_size, void* d_ws,
                              size_t ws_size, hipStream_t stream) {
  const void* x   = d_in[0];
  const void* mw0 = d_in[5];
  const void* mb0 = d_in[6];
  const void* jw0 = d_in[7];
  const void* jb0 = d_in[8];
  const void* mw1 = d_in[9];
  const void* mb1 = d_in[10];
  const void* jw1 = d_in[11];
  const void* jb1 = d_in[12];

  char* ws = (char*)d_ws;
  const size_t MB = 1u << 20;
  unsigned short* Xt0   = (unsigned short*)(ws + 0);        // 8.4 MB
  unsigned short* A1    = (unsigned short*)(ws + 9 * MB);   // 16.8 MB
  unsigned short* Wall0 = (unsigned short*)(ws + 26 * MB);  // 7.4 MB (448)
  unsigned short* Wall1 = (unsigned short*)(ws + 34 * MB);  // 14.7 MB (448)
  unsigned short* Out2  = (unsigned short*)(ws + 49 * MB);  // 16.8 MB
  unsigned short* PBg0  = (unsigned short*)(ws + 66 * MB);  // 2.1 MB
  unsigned short* PBg1  = (unsigned short*)(ws + 69 * MB);  // 4.2 MB
  unsigned short* L     = (unsigned short*)(ws + 74 * MB);  // 114 KB
  float* bias0 = (float*)(ws + 75 * MB);
  float* bias1 = bias0 + 128;
  unsigned short* V = (unsigned short*)(ws + 76 * MB);      // 4.2 MB
  unsigned short* U = (unsigned short*)(ws + 81 * MB);      // 4.2 MB
  unsigned short* T = (unsigned short*)(ws + 86 * MB);      // 1.05 MB

  mega_setup<<<5345, 256, 0, stream>>>(
      (const unsigned short*)x, mw0, jw0, mw1, jw1, mb0, jb0, mb1, jb1, L,
      bias0, bias1, PBg0, PBg1, Xt0);
  prep_gemm2<<<dim3(128, 7, 2), 256, 0, stream>>>(L, PBg0, PBg1, Wall0, Wall1);

  // ---- Layer 1 (F=64) ----
  corr_scan<64><<<dim3(72, 8), 256, 0, stream>>>(Xt0, Wall0, V, U, T);
  final_gemm<64><<<dim3(1024, 2), 256, 0, stream>>>(Xt0, Wall0, V, U, T,
                                                    bias0, A1);
  // ---- Layer 2 (F=128) ----
  corr_scan<128><<<dim3(72, 8), 256, 0, stream>>>(A1, Wall1, V, U, T);
  final_gemm<128><<<dim3(1024, 2), 256, 0, stream>>>(A1, Wall1, V, U, T,
                                                     bias1, Out2);

  // Out2 [pos=1024][m*128+g=8192] -> d_out [m][g][pos]
  transpose_out<<<dim3(256, 32), 256, 0, stream>>>(
      (const unsigned short*)x, Out2, (unsigned short*)d_out, (float*)d_out);
}